// Round 6
// baseline (262.410 us; speedup 1.0000x reference)
//
#include <hip/hip_runtime.h>

#define N_NODES 100000
#define NFEAT 256
#define NHID 128
#define NCLASS 8

#define BSH 6                          // bucket = dst >> 6 (64 nodes/bucket)
#define BUCK 64
#define NBUCK ((N_NODES + BUCK - 1) / BUCK)   // 1563
#define VX 8                           // physical XCDs
#define CAPS 224                       // per (bucket,xcd) capacity: mean 128 + 8.5 sigma
#define GSTRIDE (NBUCK * CAPS)         // 350112 ints per xcd region (896B cells = 14 lines)
#define CAPB (CAPS * VX)               // 1792 max edges per bucket in LDS sort
#define NBLK1 2048                     // scatter blocks = exact full residency (8/CU)
#define OVF_CAP 32768                  // overflow safety net (normally 0 used)

// ---------------------------------------------------------------------------
// K0: init per-(xcd,bucket) cursors + overflow counter, precompute
// WcT[c*256+f] = (W1 @ Wfc)^T and cvec = b1 @ Wfc + bfc.
__global__ __launch_bounds__(512) void init_kernel(const float* __restrict__ W1,
        const float* __restrict__ b1, const float* __restrict__ Wfc,
        const float* __restrict__ bfc, float* __restrict__ WcT,
        float* __restrict__ cvec, int* __restrict__ gcur, int* __restrict__ ovf_cnt) {
    int tid = threadIdx.x;
    if (blockIdx.x == 0) {
        __shared__ float wfs[NHID * NCLASS];
        __shared__ float bs[NHID];
        for (int i = tid; i < NHID * NCLASS; i += 512) wfs[i] = Wfc[i];
        if (tid < NHID) bs[tid] = b1[tid];
        __syncthreads();
        if (tid < NFEAT) {
            float acc[NCLASS] = {};
            for (int h = 0; h < NHID; h++) {
                float w = W1[tid * NHID + h];
                #pragma unroll
                for (int c = 0; c < NCLASS; c++) acc[c] += w * wfs[h * NCLASS + c];
            }
            #pragma unroll
            for (int c = 0; c < NCLASS; c++) WcT[c * NFEAT + tid] = acc[c];
        }
        if (tid < NCLASS) {
            float a = bfc[tid];
            for (int h = 0; h < NHID; h++) a += bs[h] * wfs[h * NCLASS + tid];
            cvec[tid] = a;
        }
    } else {
        int i = (blockIdx.x - 1) * 512 + tid;
        if (i < VX * NBUCK) {
            int g = i / NBUCK;
            int b = i - g * NBUCK;
            gcur[i] = g * GSTRIDE + b * CAPS;     // absolute cell base
        }
        if (blockIdx.x == 1 && tid == 0) *ovf_cnt = 0;
    }
}

// ---------------------------------------------------------------------------
// K1: two-pass bin, XCD-local (same structure as the 239us-passing version;
// only the bucket granularity changed).
__global__ __launch_bounds__(256) void scat_kernel(const int* __restrict__ esrc,
        const int* __restrict__ edst, int* __restrict__ gcur,
        int* __restrict__ ebufP, int* __restrict__ ovf_cnt,
        int* __restrict__ ovfbuf, int chunk, int nE) {
    __shared__ int h[NBUCK];
    __shared__ int lcur[NBUCK];
    int tid = threadIdx.x;
    int xcc;
    asm volatile("s_getreg_b32 %0, hwreg(HW_REG_XCC_ID)" : "=s"(xcc));
    xcc &= (VX - 1);
    for (int i = tid; i < NBUCK; i += 256) h[i] = 0;
    __syncthreads();
    int e0 = blockIdx.x * chunk;
    int e1 = min(e0 + chunk, nE);
    for (int e = e0 + tid * 4; e + 3 < e1; e += 1024) {
        int4 d = *(const int4*)&edst[e];
        atomicAdd(&h[d.x >> BSH], 1); atomicAdd(&h[d.y >> BSH], 1);
        atomicAdd(&h[d.z >> BSH], 1); atomicAdd(&h[d.w >> BSH], 1);
    }
    int full = e0 + ((e1 - e0) & ~3);
    if (full + tid < e1) atomicAdd(&h[edst[full + tid] >> BSH], 1);
    __syncthreads();
    const int gbase = xcc * GSTRIDE;
    for (int b = tid; b < NBUCK; b += 256) {
        int c = h[b];
        lcur[b] = c ? atomicAdd(&gcur[xcc * NBUCK + b], c) : 0;
    }
    __syncthreads();
    for (int e = e0 + tid * 4; e + 3 < e1; e += 1024) {
        int4 s = *(const int4*)&esrc[e];
        int4 d = *(const int4*)&edst[e];
        int b0 = d.x >> BSH, b1_ = d.y >> BSH, b2 = d.z >> BSH, b3 = d.w >> BSH;
        int p0 = atomicAdd(&lcur[b0], 1);
        int p1 = atomicAdd(&lcur[b1_], 1);
        int p2 = atomicAdd(&lcur[b2], 1);
        int p3 = atomicAdd(&lcur[b3], 1);
        int k0 = (s.x << BSH) | (d.x & (BUCK - 1));
        int k1 = (s.y << BSH) | (d.y & (BUCK - 1));
        int k2 = (s.z << BSH) | (d.z & (BUCK - 1));
        int k3 = (s.w << BSH) | (d.w & (BUCK - 1));
        if (p0 < gbase + b0 * CAPS + CAPS) ebufP[p0] = k0;
        else { int op = atomicAdd(ovf_cnt, 1); if (op < OVF_CAP) { ovfbuf[2*op] = k0; ovfbuf[2*op+1] = b0; } }
        if (p1 < gbase + b1_ * CAPS + CAPS) ebufP[p1] = k1;
        else { int op = atomicAdd(ovf_cnt, 1); if (op < OVF_CAP) { ovfbuf[2*op] = k1; ovfbuf[2*op+1] = b1_; } }
        if (p2 < gbase + b2 * CAPS + CAPS) ebufP[p2] = k2;
        else { int op = atomicAdd(ovf_cnt, 1); if (op < OVF_CAP) { ovfbuf[2*op] = k2; ovfbuf[2*op+1] = b2; } }
        if (p3 < gbase + b3 * CAPS + CAPS) ebufP[p3] = k3;
        else { int op = atomicAdd(ovf_cnt, 1); if (op < OVF_CAP) { ovfbuf[2*op] = k3; ovfbuf[2*op+1] = b3; } }
    }
    if (full + tid < e1) {
        int s = esrc[full + tid], d = edst[full + tid];
        int b = d >> BSH;
        int p = atomicAdd(&lcur[b], 1);
        int k = (s << BSH) | (d & (BUCK - 1));
        if (p < gbase + b * CAPS + CAPS) ebufP[p] = k;
        else { int op = atomicAdd(ovf_cnt, 1); if (op < OVF_CAP) { ovfbuf[2*op] = k; ovfbuf[2*op+1] = b; } }
    }
}

// ---------------------------------------------------------------------------
// K2: exact per-node degree per bucket -> dinv. 1563 blocks (6.1/CU).
__global__ __launch_bounds__(256) void deg_dinv_kernel(const int* __restrict__ ebufP,
        const int* __restrict__ gcur, const int* __restrict__ ovf_cnt,
        const int* __restrict__ ovfbuf, float* __restrict__ dinv) {
    __shared__ int cnt[BUCK];
    int b = blockIdx.x, tid = threadIdx.x;
    if (tid < BUCK) cnt[tid] = 0;
    __syncthreads();
    #pragma unroll
    for (int g = 0; g < VX; g++) {
        int base = g * GSTRIDE + b * CAPS;
        int end = min(gcur[g * NBUCK + b], base + CAPS);
        int n = end - base;
        const int4* p4 = (const int4*)&ebufP[base];
        int n4 = n >> 2;
        for (int k = tid; k < n4; k += 256) {
            int4 p = p4[k];
            atomicAdd(&cnt[p.x & (BUCK - 1)], 1);
            atomicAdd(&cnt[p.y & (BUCK - 1)], 1);
            atomicAdd(&cnt[p.z & (BUCK - 1)], 1);
            atomicAdd(&cnt[p.w & (BUCK - 1)], 1);
        }
        for (int k = (n4 << 2) + tid; k < n; k += 256)
            atomicAdd(&cnt[ebufP[base + k] & (BUCK - 1)], 1);
    }
    int nov = min(*ovf_cnt, OVF_CAP);
    for (int i = tid; i < nov; i += 256)
        if (ovfbuf[2 * i + 1] == b) atomicAdd(&cnt[ovfbuf[2 * i] & (BUCK - 1)], 1);
    __syncthreads();
    if (tid < BUCK) {
        int node = (b << BSH) + tid;
        if (node < N_NODES) dinv[node] = rsqrtf((float)(cnt[tid] + 1));
    }
}

// ---------------------------------------------------------------------------
// Kz (v3, unchanged): wave = 16 rows (two octets), one broadcast W ds_read
// feeds FMAs for both octets.
__global__ __launch_bounds__(256) void z_kernel(const float* __restrict__ X,
                                                const float* __restrict__ WcT,
                                                const float* __restrict__ dinv,
                                                float* __restrict__ Zs, int n) {
    __shared__ float4 wlds[NCLASS * 64];       // 8 KB
    int tid = threadIdx.x;
    #pragma unroll
    for (int i = tid; i < NCLASS * 64; i += 256)
        wlds[i] = ((const float4*)WcT)[i];
    __syncthreads();

    const int lane = tid & 63;
    const int sub  = lane & 7;
    const int rsub = lane >> 3;
    const int wbase = (blockIdx.x * 4 + (tid >> 6)) * 16;
    int rA = wbase + rsub, rB = wbase + 8 + rsub;
    bool okA = rA < n, okB = rB < n;
    int cA = okA ? rA : n - 1, cB = okB ? rB : n - 1;
    float dvA = dinv[cA], dvB = dinv[cB];

    const float4* xra = (const float4*)(X + (long)cA * NFEAT);
    const float4* xrb = (const float4*)(X + (long)cB * NFEAT);
    float4 xa[8], xb[8];
    #pragma unroll
    for (int k = 0; k < 8; k++) {
        xa[k] = xra[sub + 8 * k];
        xb[k] = xrb[sub + 8 * k];
    }

    float resA = 0.f, resB = 0.f;
    #pragma unroll
    for (int c = 0; c < NCLASS; c++) {
        float sA = 0.f, sB = 0.f;
        #pragma unroll
        for (int k = 0; k < 8; k++) {
            float4 w = wlds[c * 64 + sub + 8 * k];
            sA += xa[k].x * w.x + xa[k].y * w.y + xa[k].z * w.z + xa[k].w * w.w;
            sB += xb[k].x * w.x + xb[k].y * w.y + xb[k].z * w.z + xb[k].w * w.w;
        }
        sA += __shfl_xor(sA, 1); sA += __shfl_xor(sA, 2); sA += __shfl_xor(sA, 4);
        sB += __shfl_xor(sB, 1); sB += __shfl_xor(sB, 2); sB += __shfl_xor(sB, 4);
        if (sub == c) { resA = sA; resB = sB; }
    }
    if (okA) Zs[(long)rA * NCLASS + sub] = resA * dvA;
    if (okB) Zs[(long)rB * NCLASS + sub] = resB * dvB;
}

// ---------------------------------------------------------------------------
// Kg: fused in-LDS counting sort + gather. 64 nodes/block, 8 threads/node
// (2 half-rows x 4-way k-stride, shfl_xor reduce) -> serial chain /4.
__global__ __launch_bounds__(512) void sort_gather_kernel(
        const float* __restrict__ Zs,
        const int* __restrict__ ebufP,
        const int* __restrict__ gcur,
        const int* __restrict__ ovf_cnt,
        const int* __restrict__ ovfbuf,
        const float* __restrict__ cvec,
        float* __restrict__ out, int n) {
    __shared__ int cnt[BUCK];          // counts, then cursors
    __shared__ int off[BUCK + 1];
    __shared__ int ss[BUCK];
    __shared__ int sorted[CAPB];
    int b = blockIdx.x, tid = threadIdx.x;
    const float4* Zs4 = (const float4*)Zs;
    float4 c0v = ((const float4*)cvec)[0];
    float4 c1v = ((const float4*)cvec)[1];
    int nov = min(*ovf_cnt, OVF_CAP);

    if (tid < BUCK) cnt[tid] = 0;
    __syncthreads();
    #pragma unroll
    for (int g = 0; g < VX; g++) {
        int base = g * GSTRIDE + b * CAPS;
        int end = min(gcur[g * NBUCK + b], base + CAPS);
        int nn = end - base;
        const int4* p4 = (const int4*)&ebufP[base];
        int n4 = nn >> 2;
        for (int k = tid; k < n4; k += 512) {
            int4 p = p4[k];
            atomicAdd(&cnt[p.x & (BUCK - 1)], 1);
            atomicAdd(&cnt[p.y & (BUCK - 1)], 1);
            atomicAdd(&cnt[p.z & (BUCK - 1)], 1);
            atomicAdd(&cnt[p.w & (BUCK - 1)], 1);
        }
        for (int k = (n4 << 2) + tid; k < nn; k += 512)
            atomicAdd(&cnt[ebufP[base + k] & (BUCK - 1)], 1);
    }
    for (int i = tid; i < nov; i += 512)
        if (ovfbuf[2 * i + 1] == b) atomicAdd(&cnt[ovfbuf[2 * i] & (BUCK - 1)], 1);
    __syncthreads();

    int t = (tid < BUCK) ? cnt[tid] : 0;
    if (tid < BUCK) ss[tid] = t;
    __syncthreads();
    for (int o = 1; o < BUCK; o <<= 1) {
        int u = 0;
        if (tid < BUCK && tid >= o) u = ss[tid - o];
        __syncthreads();
        if (tid < BUCK) ss[tid] += u;
        __syncthreads();
    }
    if (tid < BUCK) {
        off[tid] = ss[tid] - t;
        cnt[tid] = ss[tid] - t;     // cursor
        if (tid == BUCK - 1) off[BUCK] = ss[tid];
    }
    __syncthreads();

    #pragma unroll
    for (int g = 0; g < VX; g++) {
        int base = g * GSTRIDE + b * CAPS;
        int end = min(gcur[g * NBUCK + b], base + CAPS);
        int nn = end - base;
        const int4* p4 = (const int4*)&ebufP[base];
        int n4 = nn >> 2;
        for (int k = tid; k < n4; k += 512) {
            int4 p = p4[k];
            int s0 = atomicAdd(&cnt[p.x & (BUCK - 1)], 1);
            int s1 = atomicAdd(&cnt[p.y & (BUCK - 1)], 1);
            int s2 = atomicAdd(&cnt[p.z & (BUCK - 1)], 1);
            int s3 = atomicAdd(&cnt[p.w & (BUCK - 1)], 1);
            sorted[s0] = p.x >> BSH;
            sorted[s1] = p.y >> BSH;
            sorted[s2] = p.z >> BSH;
            sorted[s3] = p.w >> BSH;
        }
        for (int k = (n4 << 2) + tid; k < nn; k += 512) {
            int p = ebufP[base + k];
            int slot = atomicAdd(&cnt[p & (BUCK - 1)], 1);
            sorted[slot] = p >> BSH;
        }
    }
    for (int i = tid; i < nov; i += 512) {
        if (ovfbuf[2 * i + 1] == b) {
            int p = ovfbuf[2 * i];
            int slot = atomicAdd(&cnt[p & (BUCK - 1)], 1);
            sorted[slot] = p >> BSH;
        }
    }
    __syncthreads();

    // 8 threads per node: bit0 = half-row, bits1-2 = k-stride lane
    int li = tid >> 3;
    int hh = tid & 1;
    int kk = (tid >> 1) & 3;
    int node = (b << BSH) + li;
    int k0 = (node < n) ? off[li] : 0;
    int k1 = (node < n) ? off[li + 1] : 0;
    float4 a; a.x = 0.f; a.y = 0.f; a.z = 0.f; a.w = 0.f;
    for (int k = k0 + kk; k < k1; k += 4) {
        float4 z = Zs4[sorted[k] * 2 + hh];
        a.x += z.x; a.y += z.y; a.z += z.z; a.w += z.w;
    }
    // reduce across the 4 k-stride lanes (same hh): lane bits 1 and 2
    a.x += __shfl_xor(a.x, 2); a.y += __shfl_xor(a.y, 2);
    a.z += __shfl_xor(a.z, 2); a.w += __shfl_xor(a.w, 2);
    a.x += __shfl_xor(a.x, 4); a.y += __shfl_xor(a.y, 4);
    a.z += __shfl_xor(a.z, 4); a.w += __shfl_xor(a.w, 4);
    if (kk == 0 && node < n) {
        float4 z = Zs4[node * 2 + hh];                    // self-loop
        a.x += z.x; a.y += z.y; a.z += z.z; a.w += z.w;
        float dd = rsqrtf((float)(k1 - k0 + 1));          // local degree + self
        float4 cv = hh ? c1v : c0v;
        float4 o;
        o.x = a.x * dd + cv.x; o.y = a.y * dd + cv.y;
        o.z = a.z * dd + cv.z; o.w = a.w * dd + cv.w;
        ((float4*)out)[node * 2 + hh] = o;
    }
}

// ---------------------------------------------------------------------------
extern "C" void kernel_launch(void* const* d_in, const int* in_sizes, int n_in,
                              void* d_out, int out_size, void* d_ws, size_t ws_size,
                              hipStream_t stream) {
    const float* x    = (const float*)d_in[0];   // [N, 256]
    const int*   eidx = (const int*)d_in[1];     // [2, E] (int32 on device)
    const float* W1   = (const float*)d_in[2];   // [256, 128]
    const float* b1   = (const float*)d_in[3];   // [128]
    const float* Wfc  = (const float*)d_in[4];   // [128, 8]
    const float* bfc  = (const float*)d_in[5];   // [8]
    float* out = (float*)d_out;

    const int N = N_NODES;
    const int E = in_sizes[1] / 2;

    const int* esrc = eidx;
    const int* edst = eidx + E;

    // workspace layout (~15.1 MB); every region written before read.
    float* Zs     = (float*)d_ws;                    // 800000 floats
    float* cvec   = Zs + (long)8 * N;                // 8
    float* WcT    = cvec + 8;                        // 2048 (c-major)
    float* dinv   = WcT + NCLASS * NFEAT;            // 100000
    int*   gcur   = (int*)(dinv + N);                // VX*NBUCK = 12504
    int*   ovfc   = gcur + VX * NBUCK;               // 1 (+3 pad)
    int*   ovfbuf = ovfc + 4;                        // 2*OVF_CAP
    int*   ebufP  = ovfbuf + 2 * OVF_CAP;            // VX*GSTRIDE (16B-aligned)

    const int chunk = (((E + NBLK1 - 1) / NBLK1) + 3) & ~3;   // 784 for E=1.6M

    init_kernel<<<1 + (VX * NBUCK + 511) / 512, 512, 0, stream>>>(
        W1, b1, Wfc, bfc, WcT, cvec, gcur, ovfc);
    scat_kernel<<<NBLK1, 256, 0, stream>>>(esrc, edst, gcur, ebufP, ovfc, ovfbuf, chunk, E);
    deg_dinv_kernel<<<NBUCK, 256, 0, stream>>>(ebufP, gcur, ovfc, ovfbuf, dinv);
    z_kernel<<<(N + 63) / 64, 256, 0, stream>>>(x, WcT, dinv, Zs, N);
    sort_gather_kernel<<<NBUCK, 512, 0, stream>>>(Zs, ebufP, gcur, ovfc, ovfbuf, cvec, out, N);
}

// Round 7
// 230.306 us; speedup vs baseline: 1.1394x; 1.1394x over previous
//
#include <hip/hip_runtime.h>

#define N_NODES 100000
#define NFEAT 256
#define NHID 128
#define NCLASS 8

#define BSH 8                          // bucket = dst >> 8 (256 nodes/bucket)
#define BUCK 256
#define NBUCK ((N_NODES + BUCK - 1) / BUCK)   // 391
#define VX 8                           // physical XCDs
#define CAPS 704                       // per (bucket,xcd) capacity: mean 513 + 8.4 sigma
#define GSTRIDE (NBUCK * CAPS)         // 275264 ints per xcd region (2816B cells = 44 lines)
#define CAPB (CAPS * VX)               // 5632 max edges per bucket in LDS sort
#define NBLK1 2048                     // scatter blocks = exact full residency (8/CU)
#define OVF_CAP 32768                  // overflow safety net (normally 0 used)

// ---------------------------------------------------------------------------
// K0: init per-(xcd,bucket) cursors + overflow counter, precompute
// Wf[f*8+c] = (W1 @ Wfc)[f][c] (f-major -> z's W reads are wave-uniform
// scalar loads) and cvec = b1 @ Wfc + bfc.
__global__ __launch_bounds__(512) void init_kernel(const float* __restrict__ W1,
        const float* __restrict__ b1, const float* __restrict__ Wfc,
        const float* __restrict__ bfc, float* __restrict__ Wf,
        float* __restrict__ cvec, int* __restrict__ gcur, int* __restrict__ ovf_cnt) {
    int tid = threadIdx.x;
    if (blockIdx.x == 0) {
        __shared__ float wfs[NHID * NCLASS];
        __shared__ float bs[NHID];
        for (int i = tid; i < NHID * NCLASS; i += 512) wfs[i] = Wfc[i];
        if (tid < NHID) bs[tid] = b1[tid];
        __syncthreads();
        if (tid < NFEAT) {
            float acc[NCLASS] = {};
            for (int h = 0; h < NHID; h++) {
                float w = W1[tid * NHID + h];
                #pragma unroll
                for (int c = 0; c < NCLASS; c++) acc[c] += w * wfs[h * NCLASS + c];
            }
            #pragma unroll
            for (int c = 0; c < NCLASS; c++) Wf[tid * NCLASS + c] = acc[c];
        }
        if (tid < NCLASS) {
            float a = bfc[tid];
            for (int h = 0; h < NHID; h++) a += bs[h] * wfs[h * NCLASS + tid];
            cvec[tid] = a;
        }
    } else {
        int i = (blockIdx.x - 1) * 512 + tid;
        if (i < VX * NBUCK) {
            int g = i / NBUCK;
            int b = i - g * NBUCK;
            gcur[i] = g * GSTRIDE + b * CAPS;     // absolute cell base
        }
        if (blockIdx.x == 1 && tid == 0) *ovf_cnt = 0;
    }
}

// ---------------------------------------------------------------------------
// K1: two-pass bin, XCD-local (unchanged from the round-5 232.8us version).
__global__ __launch_bounds__(256) void scat_kernel(const int* __restrict__ esrc,
        const int* __restrict__ edst, int* __restrict__ gcur,
        int* __restrict__ ebufP, int* __restrict__ ovf_cnt,
        int* __restrict__ ovfbuf, int chunk, int nE) {
    __shared__ int h[NBUCK];
    __shared__ int lcur[NBUCK];
    int tid = threadIdx.x;
    int xcc;
    asm volatile("s_getreg_b32 %0, hwreg(HW_REG_XCC_ID)" : "=s"(xcc));
    xcc &= (VX - 1);
    for (int i = tid; i < NBUCK; i += 256) h[i] = 0;
    __syncthreads();
    int e0 = blockIdx.x * chunk;
    int e1 = min(e0 + chunk, nE);
    for (int e = e0 + tid * 4; e + 3 < e1; e += 1024) {
        int4 d = *(const int4*)&edst[e];
        atomicAdd(&h[d.x >> BSH], 1); atomicAdd(&h[d.y >> BSH], 1);
        atomicAdd(&h[d.z >> BSH], 1); atomicAdd(&h[d.w >> BSH], 1);
    }
    int full = e0 + ((e1 - e0) & ~3);
    if (full + tid < e1) atomicAdd(&h[edst[full + tid] >> BSH], 1);
    __syncthreads();
    const int gbase = xcc * GSTRIDE;
    for (int b = tid; b < NBUCK; b += 256) {
        int c = h[b];
        lcur[b] = c ? atomicAdd(&gcur[xcc * NBUCK + b], c) : 0;
    }
    __syncthreads();
    for (int e = e0 + tid * 4; e + 3 < e1; e += 1024) {
        int4 s = *(const int4*)&esrc[e];
        int4 d = *(const int4*)&edst[e];
        int b0 = d.x >> BSH, b1_ = d.y >> BSH, b2 = d.z >> BSH, b3 = d.w >> BSH;
        int p0 = atomicAdd(&lcur[b0], 1);
        int p1 = atomicAdd(&lcur[b1_], 1);
        int p2 = atomicAdd(&lcur[b2], 1);
        int p3 = atomicAdd(&lcur[b3], 1);
        int k0 = (s.x << BSH) | (d.x & (BUCK - 1));
        int k1 = (s.y << BSH) | (d.y & (BUCK - 1));
        int k2 = (s.z << BSH) | (d.z & (BUCK - 1));
        int k3 = (s.w << BSH) | (d.w & (BUCK - 1));
        if (p0 < gbase + b0 * CAPS + CAPS) ebufP[p0] = k0;
        else { int op = atomicAdd(ovf_cnt, 1); if (op < OVF_CAP) { ovfbuf[2*op] = k0; ovfbuf[2*op+1] = b0; } }
        if (p1 < gbase + b1_ * CAPS + CAPS) ebufP[p1] = k1;
        else { int op = atomicAdd(ovf_cnt, 1); if (op < OVF_CAP) { ovfbuf[2*op] = k1; ovfbuf[2*op+1] = b1_; } }
        if (p2 < gbase + b2 * CAPS + CAPS) ebufP[p2] = k2;
        else { int op = atomicAdd(ovf_cnt, 1); if (op < OVF_CAP) { ovfbuf[2*op] = k2; ovfbuf[2*op+1] = b2; } }
        if (p3 < gbase + b3 * CAPS + CAPS) ebufP[p3] = k3;
        else { int op = atomicAdd(ovf_cnt, 1); if (op < OVF_CAP) { ovfbuf[2*op] = k3; ovfbuf[2*op+1] = b3; } }
    }
    if (full + tid < e1) {
        int s = esrc[full + tid], d = edst[full + tid];
        int b = d >> BSH;
        int p = atomicAdd(&lcur[b], 1);
        int k = (s << BSH) | (d & (BUCK - 1));
        if (p < gbase + b * CAPS + CAPS) ebufP[p] = k;
        else { int op = atomicAdd(ovf_cnt, 1); if (op < OVF_CAP) { ovfbuf[2*op] = k; ovfbuf[2*op+1] = b; } }
    }
}

// ---------------------------------------------------------------------------
// K2: exact per-node degree per bucket -> dinv. int4 segment reads.
__global__ __launch_bounds__(512) void deg_dinv_kernel(const int* __restrict__ ebufP,
        const int* __restrict__ gcur, const int* __restrict__ ovf_cnt,
        const int* __restrict__ ovfbuf, float* __restrict__ dinv) {
    __shared__ int cnt[BUCK];
    int b = blockIdx.x, tid = threadIdx.x;
    if (tid < BUCK) cnt[tid] = 0;
    __syncthreads();
    #pragma unroll
    for (int g = 0; g < VX; g++) {
        int base = g * GSTRIDE + b * CAPS;
        int end = min(gcur[g * NBUCK + b], base + CAPS);
        int n = end - base;
        const int4* p4 = (const int4*)&ebufP[base];
        int n4 = n >> 2;
        for (int k = tid; k < n4; k += 512) {
            int4 p = p4[k];
            atomicAdd(&cnt[p.x & (BUCK - 1)], 1);
            atomicAdd(&cnt[p.y & (BUCK - 1)], 1);
            atomicAdd(&cnt[p.z & (BUCK - 1)], 1);
            atomicAdd(&cnt[p.w & (BUCK - 1)], 1);
        }
        for (int k = (n4 << 2) + tid; k < n; k += 512)
            atomicAdd(&cnt[ebufP[base + k] & (BUCK - 1)], 1);
    }
    int nov = min(*ovf_cnt, OVF_CAP);
    for (int i = tid; i < nov; i += 512)
        if (ovfbuf[2 * i + 1] == b) atomicAdd(&cnt[ovfbuf[2 * i] & (BUCK - 1)], 1);
    __syncthreads();
    if (tid < BUCK) {
        int node = (b << BSH) + tid;
        if (node < N_NODES) dinv[node] = rsqrtf((float)(cnt[tid] + 1));
    }
}

// ---------------------------------------------------------------------------
// Kz (v5): lane-per-row, zero LDS, zero shuffles. Each lane owns one row;
// W index depends only on loop counter -> wave-uniform -> s_load from K$
// (8 KB Wf fully cached); FMAs are v_fmac(v,s,v). 64 independent float4
// loads per thread (#pragma unroll 8 keeps ~8 in flight). 1563 one-wave
// blocks = balanced ~6/CU.
__global__ __launch_bounds__(64) void z_kernel(const float* __restrict__ X,
                                               const float* __restrict__ Wf,
                                               const float* __restrict__ dinv,
                                               float* __restrict__ Zs, int n) {
    int row = blockIdx.x * 64 + threadIdx.x;
    bool ok = row < n;
    int r = ok ? row : n - 1;
    const float4* xr = (const float4*)(X + (long)r * NFEAT);
    float dv = dinv[r];
    float acc[NCLASS] = {};
    #pragma unroll 8
    for (int k = 0; k < 64; k++) {
        float4 x4 = xr[k];
        const float* w = Wf + k * 32;          // uniform -> scalar loads
        #pragma unroll
        for (int c = 0; c < NCLASS; c++)
            acc[c] += x4.x * w[c] + x4.y * w[8 + c]
                    + x4.z * w[16 + c] + x4.w * w[24 + c];
    }
    if (ok) {
        float4 o0, o1;
        o0.x = acc[0] * dv; o0.y = acc[1] * dv; o0.z = acc[2] * dv; o0.w = acc[3] * dv;
        o1.x = acc[4] * dv; o1.y = acc[5] * dv; o1.z = acc[6] * dv; o1.w = acc[7] * dv;
        ((float4*)Zs)[(long)row * 2]     = o0;
        ((float4*)Zs)[(long)row * 2 + 1] = o1;
    }
}

// ---------------------------------------------------------------------------
// Kg: fused in-LDS counting sort + register-accumulate gather per bucket
// (unchanged from the round-5 232.8us version).
__global__ __launch_bounds__(512) void sort_gather_kernel(
        const float* __restrict__ Zs,
        const int* __restrict__ ebufP,
        const int* __restrict__ gcur,
        const int* __restrict__ ovf_cnt,
        const int* __restrict__ ovfbuf,
        const float* __restrict__ cvec,
        float* __restrict__ out, int n) {
    __shared__ int cnt[BUCK];          // counts, then cursors
    __shared__ int off[BUCK + 1];
    __shared__ int ss[BUCK];
    __shared__ int sorted[CAPB];
    int b = blockIdx.x, tid = threadIdx.x;
    const float4* Zs4 = (const float4*)Zs;
    float4 c0v = ((const float4*)cvec)[0];
    float4 c1v = ((const float4*)cvec)[1];
    int nov = min(*ovf_cnt, OVF_CAP);

    if (tid < BUCK) cnt[tid] = 0;
    __syncthreads();
    #pragma unroll
    for (int g = 0; g < VX; g++) {
        int base = g * GSTRIDE + b * CAPS;
        int end = min(gcur[g * NBUCK + b], base + CAPS);
        int nn = end - base;
        const int4* p4 = (const int4*)&ebufP[base];
        int n4 = nn >> 2;
        for (int k = tid; k < n4; k += 512) {
            int4 p = p4[k];
            atomicAdd(&cnt[p.x & (BUCK - 1)], 1);
            atomicAdd(&cnt[p.y & (BUCK - 1)], 1);
            atomicAdd(&cnt[p.z & (BUCK - 1)], 1);
            atomicAdd(&cnt[p.w & (BUCK - 1)], 1);
        }
        for (int k = (n4 << 2) + tid; k < nn; k += 512)
            atomicAdd(&cnt[ebufP[base + k] & (BUCK - 1)], 1);
    }
    for (int i = tid; i < nov; i += 512)
        if (ovfbuf[2 * i + 1] == b) atomicAdd(&cnt[ovfbuf[2 * i] & (BUCK - 1)], 1);
    __syncthreads();

    int t = (tid < BUCK) ? cnt[tid] : 0;
    if (tid < BUCK) ss[tid] = t;
    __syncthreads();
    for (int o = 1; o < BUCK; o <<= 1) {
        int u = 0;
        if (tid < BUCK && tid >= o) u = ss[tid - o];
        __syncthreads();
        if (tid < BUCK) ss[tid] += u;
        __syncthreads();
    }
    if (tid < BUCK) {
        off[tid] = ss[tid] - t;
        cnt[tid] = ss[tid] - t;     // cursor
        if (tid == BUCK - 1) off[BUCK] = ss[tid];
    }
    __syncthreads();

    #pragma unroll
    for (int g = 0; g < VX; g++) {
        int base = g * GSTRIDE + b * CAPS;
        int end = min(gcur[g * NBUCK + b], base + CAPS);
        int nn = end - base;
        const int4* p4 = (const int4*)&ebufP[base];
        int n4 = nn >> 2;
        for (int k = tid; k < n4; k += 512) {
            int4 p = p4[k];
            int s0 = atomicAdd(&cnt[p.x & (BUCK - 1)], 1);
            int s1 = atomicAdd(&cnt[p.y & (BUCK - 1)], 1);
            int s2 = atomicAdd(&cnt[p.z & (BUCK - 1)], 1);
            int s3 = atomicAdd(&cnt[p.w & (BUCK - 1)], 1);
            sorted[s0] = p.x >> BSH;
            sorted[s1] = p.y >> BSH;
            sorted[s2] = p.z >> BSH;
            sorted[s3] = p.w >> BSH;
        }
        for (int k = (n4 << 2) + tid; k < nn; k += 512) {
            int p = ebufP[base + k];
            int slot = atomicAdd(&cnt[p & (BUCK - 1)], 1);
            sorted[slot] = p >> BSH;
        }
    }
    for (int i = tid; i < nov; i += 512) {
        if (ovfbuf[2 * i + 1] == b) {
            int p = ovfbuf[2 * i];
            int slot = atomicAdd(&cnt[p & (BUCK - 1)], 1);
            sorted[slot] = p >> BSH;
        }
    }
    __syncthreads();

    int li = tid >> 1;
    int hh = tid & 1;
    int node = (b << BSH) + li;
    if (node < n) {
        int k0 = off[li], k1 = off[li + 1];
        float4 a = Zs4[node * 2 + hh];                    // self-loop
        int k = k0;
        for (; k + 1 < k1; k += 2) {
            int s0 = sorted[k], s1 = sorted[k + 1];
            float4 z0 = Zs4[s0 * 2 + hh];
            float4 z1 = Zs4[s1 * 2 + hh];
            a.x += z0.x + z1.x; a.y += z0.y + z1.y;
            a.z += z0.z + z1.z; a.w += z0.w + z1.w;
        }
        if (k < k1) {
            float4 z = Zs4[sorted[k] * 2 + hh];
            a.x += z.x; a.y += z.y; a.z += z.z; a.w += z.w;
        }
        float dd = rsqrtf((float)(k1 - k0 + 1));          // local degree + self
        float4 cv = hh ? c1v : c0v;
        float4 o;
        o.x = a.x * dd + cv.x; o.y = a.y * dd + cv.y;
        o.z = a.z * dd + cv.z; o.w = a.w * dd + cv.w;
        ((float4*)out)[node * 2 + hh] = o;
    }
}

// ---------------------------------------------------------------------------
extern "C" void kernel_launch(void* const* d_in, const int* in_sizes, int n_in,
                              void* d_out, int out_size, void* d_ws, size_t ws_size,
                              hipStream_t stream) {
    const float* x    = (const float*)d_in[0];   // [N, 256]
    const int*   eidx = (const int*)d_in[1];     // [2, E] (int32 on device)
    const float* W1   = (const float*)d_in[2];   // [256, 128]
    const float* b1   = (const float*)d_in[3];   // [128]
    const float* Wfc  = (const float*)d_in[4];   // [128, 8]
    const float* bfc  = (const float*)d_in[5];   // [8]
    float* out = (float*)d_out;

    const int N = N_NODES;
    const int E = in_sizes[1] / 2;

    const int* esrc = eidx;
    const int* edst = eidx + E;

    // workspace layout (~12.7 MB); every region written before read.
    float* Zs     = (float*)d_ws;                    // 800000 floats
    float* cvec   = Zs + (long)8 * N;                // 8
    float* Wf     = cvec + 8;                        // 2048 (f-major)
    float* dinv   = Wf + NFEAT * NCLASS;             // 100000
    int*   gcur   = (int*)(dinv + N);                // 3128
    int*   ovfc   = gcur + VX * NBUCK;               // 1 (+3 pad)
    int*   ovfbuf = ovfc + 4;                        // 2*OVF_CAP
    int*   ebufP  = ovfbuf + 2 * OVF_CAP;            // VX*GSTRIDE (16B-aligned)

    const int chunk = (((E + NBLK1 - 1) / NBLK1) + 3) & ~3;   // 784 for E=1.6M

    init_kernel<<<1 + (VX * NBUCK + 511) / 512, 512, 0, stream>>>(
        W1, b1, Wfc, bfc, Wf, cvec, gcur, ovfc);
    scat_kernel<<<NBLK1, 256, 0, stream>>>(esrc, edst, gcur, ebufP, ovfc, ovfbuf, chunk, E);
    deg_dinv_kernel<<<NBUCK, 512, 0, stream>>>(ebufP, gcur, ovfc, ovfbuf, dinv);
    z_kernel<<<(N + 63) / 64, 64, 0, stream>>>(x, Wf, dinv, Zs, N);
    sort_gather_kernel<<<NBUCK, 512, 0, stream>>>(Zs, ebufP, gcur, ovfc, ovfbuf, cvec, out, N);
}

// Round 10
// 219.829 us; speedup vs baseline: 1.1937x; 1.0477x over previous
//
#include <hip/hip_runtime.h>

#define N_NODES 100000
#define NFEAT 256
#define NHID 128
#define NCLASS 8

#define BSH 8                          // bucket = dst >> 8 (256 nodes/bucket)
#define BUCK 256
#define NBUCK ((N_NODES + BUCK - 1) / BUCK)   // 391
#define VX 8                           // physical XCDs
#define CAPS 704                       // per (bucket,xcd) capacity: mean 513 + 8.4 sigma
#define GSTRIDE (NBUCK * CAPS)         // 275264 ints per xcd region (2816B cells = 44 lines)
#define CAPB (CAPS * VX)               // 5632 max edges per bucket in LDS sort
#define NBLK1 2048                     // scatter blocks
#define ZBLKS ((N_NODES + 255) / 256)  // 391 z blocks (256 rows each)
#define OVF_CAP 32768                  // overflow safety net (normally 0 used)

// ---------------------------------------------------------------------------
// K0: init per-(xcd,bucket) cursors + overflow counter, precompute
// Wf[f*8+c] = (W1 @ Wfc)[f][c] (f-major -> z's W reads are wave-uniform
// scalar loads) and cvec = b1 @ Wfc + bfc.
__global__ __launch_bounds__(512) void init_kernel(const float* __restrict__ W1,
        const float* __restrict__ b1, const float* __restrict__ Wfc,
        const float* __restrict__ bfc, float* __restrict__ Wf,
        float* __restrict__ cvec, int* __restrict__ gcur, int* __restrict__ ovf_cnt) {
    int tid = threadIdx.x;
    if (blockIdx.x == 0) {
        __shared__ float wfs[NHID * NCLASS];
        __shared__ float bs[NHID];
        for (int i = tid; i < NHID * NCLASS; i += 512) wfs[i] = Wfc[i];
        if (tid < NHID) bs[tid] = b1[tid];
        __syncthreads();
        if (tid < NFEAT) {
            float acc[NCLASS] = {};
            for (int h = 0; h < NHID; h++) {
                float w = W1[tid * NHID + h];
                #pragma unroll
                for (int c = 0; c < NCLASS; c++) acc[c] += w * wfs[h * NCLASS + c];
            }
            #pragma unroll
            for (int c = 0; c < NCLASS; c++) Wf[tid * NCLASS + c] = acc[c];
        }
        if (tid < NCLASS) {
            float a = bfc[tid];
            for (int h = 0; h < NHID; h++) a += bs[h] * wfs[h * NCLASS + tid];
            cvec[tid] = a;
        }
    } else {
        int i = (blockIdx.x - 1) * 512 + tid;
        if (i < VX * NBUCK) {
            int g = i / NBUCK;
            int b = i - g * NBUCK;
            gcur[i] = g * GSTRIDE + b * CAPS;     // absolute cell base
        }
        if (blockIdx.x == 1 && tid == 0) *ovf_cnt = 0;
    }
}

// ---------------------------------------------------------------------------
// K1 (fused): blocks [0,ZBLKS) run z (UNSCALED Zs = X @ Wc — no dinv
// dependency); blocks [ZBLKS, ZBLKS+NBLK1) run the XCD-local two-pass bin.
// z blocks dispatch first so every CU co-schedules latency-bound scat waves
// with VALU/load-heavy z waves (separate pipes overlap).
__global__ __launch_bounds__(256) void scat_z_kernel(const int* __restrict__ esrc,
        const int* __restrict__ edst, int* __restrict__ gcur,
        int* __restrict__ ebufP, int* __restrict__ ovf_cnt,
        int* __restrict__ ovfbuf,
        const float* __restrict__ X, const float* __restrict__ Wf,
        float* __restrict__ Zs, int chunk, int nE, int n) {
    __shared__ int h[NBUCK];
    __shared__ int lcur[NBUCK];
    int tid = threadIdx.x;

    if (blockIdx.x < ZBLKS) {
        // ---- z part: lane-per-row, zero LDS use, scalar-operand W (K$) ----
        int row = blockIdx.x * 256 + tid;
        bool ok = row < n;
        int r = ok ? row : n - 1;
        const float4* xr = (const float4*)(X + (long)r * NFEAT);
        float acc[NCLASS] = {};
        #pragma unroll 8
        for (int k = 0; k < 64; k++) {
            float4 x4 = xr[k];
            const float* w = Wf + k * 32;          // uniform -> scalar loads
            #pragma unroll
            for (int c = 0; c < NCLASS; c++)
                acc[c] += x4.x * w[c] + x4.y * w[8 + c]
                        + x4.z * w[16 + c] + x4.w * w[24 + c];
        }
        if (ok) {
            float4 o0, o1;
            o0.x = acc[0]; o0.y = acc[1]; o0.z = acc[2]; o0.w = acc[3];
            o1.x = acc[4]; o1.y = acc[5]; o1.z = acc[6]; o1.w = acc[7];
            ((float4*)Zs)[(long)row * 2]     = o0;
            ((float4*)Zs)[(long)row * 2 + 1] = o1;
        }
    } else {
        // ---- scat part (unchanged logic; block id shifted) ----
        int bid = blockIdx.x - ZBLKS;
        int xcc;
        asm volatile("s_getreg_b32 %0, hwreg(HW_REG_XCC_ID)" : "=s"(xcc));
        xcc &= (VX - 1);
        for (int i = tid; i < NBUCK; i += 256) h[i] = 0;
        __syncthreads();
        int e0 = bid * chunk;
        int e1 = min(e0 + chunk, nE);
        for (int e = e0 + tid * 4; e + 3 < e1; e += 1024) {
            int4 d = *(const int4*)&edst[e];
            atomicAdd(&h[d.x >> BSH], 1); atomicAdd(&h[d.y >> BSH], 1);
            atomicAdd(&h[d.z >> BSH], 1); atomicAdd(&h[d.w >> BSH], 1);
        }
        int full = e0 + ((e1 - e0) & ~3);
        if (full + tid < e1) atomicAdd(&h[edst[full + tid] >> BSH], 1);
        __syncthreads();
        const int gbase = xcc * GSTRIDE;
        for (int b = tid; b < NBUCK; b += 256) {
            int c = h[b];
            lcur[b] = c ? atomicAdd(&gcur[xcc * NBUCK + b], c) : 0;
        }
        __syncthreads();
        for (int e = e0 + tid * 4; e + 3 < e1; e += 1024) {
            int4 s = *(const int4*)&esrc[e];
            int4 d = *(const int4*)&edst[e];
            int b0 = d.x >> BSH, b1_ = d.y >> BSH, b2 = d.z >> BSH, b3 = d.w >> BSH;
            int p0 = atomicAdd(&lcur[b0], 1);
            int p1 = atomicAdd(&lcur[b1_], 1);
            int p2 = atomicAdd(&lcur[b2], 1);
            int p3 = atomicAdd(&lcur[b3], 1);
            int k0 = (s.x << BSH) | (d.x & (BUCK - 1));
            int k1 = (s.y << BSH) | (d.y & (BUCK - 1));
            int k2 = (s.z << BSH) | (d.z & (BUCK - 1));
            int k3 = (s.w << BSH) | (d.w & (BUCK - 1));
            if (p0 < gbase + b0 * CAPS + CAPS) ebufP[p0] = k0;
            else { int op = atomicAdd(ovf_cnt, 1); if (op < OVF_CAP) { ovfbuf[2*op] = k0; ovfbuf[2*op+1] = b0; } }
            if (p1 < gbase + b1_ * CAPS + CAPS) ebufP[p1] = k1;
            else { int op = atomicAdd(ovf_cnt, 1); if (op < OVF_CAP) { ovfbuf[2*op] = k1; ovfbuf[2*op+1] = b1_; } }
            if (p2 < gbase + b2 * CAPS + CAPS) ebufP[p2] = k2;
            else { int op = atomicAdd(ovf_cnt, 1); if (op < OVF_CAP) { ovfbuf[2*op] = k2; ovfbuf[2*op+1] = b2; } }
            if (p3 < gbase + b3 * CAPS + CAPS) ebufP[p3] = k3;
            else { int op = atomicAdd(ovf_cnt, 1); if (op < OVF_CAP) { ovfbuf[2*op] = k3; ovfbuf[2*op+1] = b3; } }
        }
        if (full + tid < e1) {
            int s = esrc[full + tid], d = edst[full + tid];
            int b = d >> BSH;
            int p = atomicAdd(&lcur[b], 1);
            int k = (s << BSH) | (d & (BUCK - 1));
            if (p < gbase + b * CAPS + CAPS) ebufP[p] = k;
            else { int op = atomicAdd(ovf_cnt, 1); if (op < OVF_CAP) { ovfbuf[2*op] = k; ovfbuf[2*op+1] = b; } }
        }
    }
}

// ---------------------------------------------------------------------------
// K2: exact per-node degree per bucket -> dinv. int4 segment reads.
__global__ __launch_bounds__(512) void deg_dinv_kernel(const int* __restrict__ ebufP,
        const int* __restrict__ gcur, const int* __restrict__ ovf_cnt,
        const int* __restrict__ ovfbuf, float* __restrict__ dinv) {
    __shared__ int cnt[BUCK];
    int b = blockIdx.x, tid = threadIdx.x;
    if (tid < BUCK) cnt[tid] = 0;
    __syncthreads();
    #pragma unroll
    for (int g = 0; g < VX; g++) {
        int base = g * GSTRIDE + b * CAPS;
        int end = min(gcur[g * NBUCK + b], base + CAPS);
        int n = end - base;
        const int4* p4 = (const int4*)&ebufP[base];
        int n4 = n >> 2;
        for (int k = tid; k < n4; k += 512) {
            int4 p = p4[k];
            atomicAdd(&cnt[p.x & (BUCK - 1)], 1);
            atomicAdd(&cnt[p.y & (BUCK - 1)], 1);
            atomicAdd(&cnt[p.z & (BUCK - 1)], 1);
            atomicAdd(&cnt[p.w & (BUCK - 1)], 1);
        }
        for (int k = (n4 << 2) + tid; k < n; k += 512)
            atomicAdd(&cnt[ebufP[base + k] & (BUCK - 1)], 1);
    }
    int nov = min(*ovf_cnt, OVF_CAP);
    for (int i = tid; i < nov; i += 512)
        if (ovfbuf[2 * i + 1] == b) atomicAdd(&cnt[ovfbuf[2 * i] & (BUCK - 1)], 1);
    __syncthreads();
    if (tid < BUCK) {
        int node = (b << BSH) + tid;
        if (node < N_NODES) dinv[node] = rsqrtf((float)(cnt[tid] + 1));
    }
}

// ---------------------------------------------------------------------------
// Kg: fused in-LDS counting sort + gather. Zs is UNSCALED, so each neighbor
// contribution is dinv[src] * Z[src] (4B L2-resident load per neighbor);
// self term uses local dd (== dinv[node]).
__global__ __launch_bounds__(512) void sort_gather_kernel(
        const float* __restrict__ Zs,
        const int* __restrict__ ebufP,
        const int* __restrict__ gcur,
        const int* __restrict__ ovf_cnt,
        const int* __restrict__ ovfbuf,
        const float* __restrict__ dinv,
        const float* __restrict__ cvec,
        float* __restrict__ out, int n) {
    __shared__ int cnt[BUCK];          // counts, then cursors
    __shared__ int off[BUCK + 1];
    __shared__ int ss[BUCK];
    __shared__ int sorted[CAPB];
    int b = blockIdx.x, tid = threadIdx.x;
    const float4* Zs4 = (const float4*)Zs;
    float4 c0v = ((const float4*)cvec)[0];
    float4 c1v = ((const float4*)cvec)[1];
    int nov = min(*ovf_cnt, OVF_CAP);

    if (tid < BUCK) cnt[tid] = 0;
    __syncthreads();
    #pragma unroll
    for (int g = 0; g < VX; g++) {
        int base = g * GSTRIDE + b * CAPS;
        int end = min(gcur[g * NBUCK + b], base + CAPS);
        int nn = end - base;
        const int4* p4 = (const int4*)&ebufP[base];
        int n4 = nn >> 2;
        for (int k = tid; k < n4; k += 512) {
            int4 p = p4[k];
            atomicAdd(&cnt[p.x & (BUCK - 1)], 1);
            atomicAdd(&cnt[p.y & (BUCK - 1)], 1);
            atomicAdd(&cnt[p.z & (BUCK - 1)], 1);
            atomicAdd(&cnt[p.w & (BUCK - 1)], 1);
        }
        for (int k = (n4 << 2) + tid; k < nn; k += 512)
            atomicAdd(&cnt[ebufP[base + k] & (BUCK - 1)], 1);
    }
    for (int i = tid; i < nov; i += 512)
        if (ovfbuf[2 * i + 1] == b) atomicAdd(&cnt[ovfbuf[2 * i] & (BUCK - 1)], 1);
    __syncthreads();

    int t = (tid < BUCK) ? cnt[tid] : 0;
    if (tid < BUCK) ss[tid] = t;
    __syncthreads();
    for (int o = 1; o < BUCK; o <<= 1) {
        int u = 0;
        if (tid < BUCK && tid >= o) u = ss[tid - o];
        __syncthreads();
        if (tid < BUCK) ss[tid] += u;
        __syncthreads();
    }
    if (tid < BUCK) {
        off[tid] = ss[tid] - t;
        cnt[tid] = ss[tid] - t;     // cursor
        if (tid == BUCK - 1) off[BUCK] = ss[tid];
    }
    __syncthreads();

    #pragma unroll
    for (int g = 0; g < VX; g++) {
        int base = g * GSTRIDE + b * CAPS;
        int end = min(gcur[g * NBUCK + b], base + CAPS);
        int nn = end - base;
        const int4* p4 = (const int4*)&ebufP[base];
        int n4 = nn >> 2;
        for (int k = tid; k < n4; k += 512) {
            int4 p = p4[k];
            int s0 = atomicAdd(&cnt[p.x & (BUCK - 1)], 1);
            int s1 = atomicAdd(&cnt[p.y & (BUCK - 1)], 1);
            int s2 = atomicAdd(&cnt[p.z & (BUCK - 1)], 1);
            int s3 = atomicAdd(&cnt[p.w & (BUCK - 1)], 1);
            sorted[s0] = p.x >> BSH;
            sorted[s1] = p.y >> BSH;
            sorted[s2] = p.z >> BSH;
            sorted[s3] = p.w >> BSH;
        }
        for (int k = (n4 << 2) + tid; k < nn; k += 512) {
            int p = ebufP[base + k];
            int slot = atomicAdd(&cnt[p & (BUCK - 1)], 1);
            sorted[slot] = p >> BSH;
        }
    }
    for (int i = tid; i < nov; i += 512) {
        if (ovfbuf[2 * i + 1] == b) {
            int p = ovfbuf[2 * i];
            int slot = atomicAdd(&cnt[p & (BUCK - 1)], 1);
            sorted[slot] = p >> BSH;
        }
    }
    __syncthreads();

    int li = tid >> 1;
    int hh = tid & 1;
    int node = (b << BSH) + li;
    if (node < n) {
        int k0 = off[li], k1 = off[li + 1];
        float4 a; a.x = 0.f; a.y = 0.f; a.z = 0.f; a.w = 0.f;
        int k = k0;
        for (; k + 1 < k1; k += 2) {
            int s0 = sorted[k], s1 = sorted[k + 1];
            float dv0 = dinv[s0], dv1 = dinv[s1];
            float4 z0 = Zs4[s0 * 2 + hh];
            float4 z1 = Zs4[s1 * 2 + hh];
            a.x += dv0 * z0.x + dv1 * z1.x; a.y += dv0 * z0.y + dv1 * z1.y;
            a.z += dv0 * z0.z + dv1 * z1.z; a.w += dv0 * z0.w + dv1 * z1.w;
        }
        if (k < k1) {
            int s = sorted[k];
            float dv = dinv[s];
            float4 z = Zs4[s * 2 + hh];
            a.x += dv * z.x; a.y += dv * z.y; a.z += dv * z.z; a.w += dv * z.w;
        }
        float dd = rsqrtf((float)(k1 - k0 + 1));          // == dinv[node]
        float4 zs = Zs4[node * 2 + hh];                   // self-loop (unscaled)
        a.x += dd * zs.x; a.y += dd * zs.y;
        a.z += dd * zs.z; a.w += dd * zs.w;
        float4 cv = hh ? c1v : c0v;
        float4 o;
        o.x = a.x * dd + cv.x; o.y = a.y * dd + cv.y;
        o.z = a.z * dd + cv.z; o.w = a.w * dd + cv.w;
        ((float4*)out)[node * 2 + hh] = o;
    }
}

// ---------------------------------------------------------------------------
extern "C" void kernel_launch(void* const* d_in, const int* in_sizes, int n_in,
                              void* d_out, int out_size, void* d_ws, size_t ws_size,
                              hipStream_t stream) {
    const float* x    = (const float*)d_in[0];   // [N, 256]
    const int*   eidx = (const int*)d_in[1];     // [2, E] (int32 on device)
    const float* W1   = (const float*)d_in[2];   // [256, 128]
    const float* b1   = (const float*)d_in[3];   // [128]
    const float* Wfc  = (const float*)d_in[4];   // [128, 8]
    const float* bfc  = (const float*)d_in[5];   // [8]
    float* out = (float*)d_out;

    const int N = N_NODES;
    const int E = in_sizes[1] / 2;

    const int* esrc = eidx;
    const int* edst = eidx + E;

    // workspace layout (~12.7 MB); every region written before read.
    float* Zs     = (float*)d_ws;                    // 800000 floats (UNSCALED)
    float* cvec   = Zs + (long)8 * N;                // 8
    float* Wf     = cvec + 8;                        // 2048 (f-major)
    float* dinv   = Wf + NFEAT * NCLASS;             // 100000
    int*   gcur   = (int*)(dinv + N);                // 3128
    int*   ovfc   = gcur + VX * NBUCK;               // 1 (+3 pad)
    int*   ovfbuf = ovfc + 4;                        // 2*OVF_CAP
    int*   ebufP  = ovfbuf + 2 * OVF_CAP;            // VX*GSTRIDE (16B-aligned)

    const int chunk = (((E + NBLK1 - 1) / NBLK1) + 3) & ~3;   // 784 for E=1.6M

    init_kernel<<<1 + (VX * NBUCK + 511) / 512, 512, 0, stream>>>(
        W1, b1, Wfc, bfc, Wf, cvec, gcur, ovfc);
    scat_z_kernel<<<ZBLKS + NBLK1, 256, 0, stream>>>(
        esrc, edst, gcur, ebufP, ovfc, ovfbuf, x, Wf, Zs, chunk, E, N);
    deg_dinv_kernel<<<NBUCK, 512, 0, stream>>>(ebufP, gcur, ovfc, ovfbuf, dinv);
    sort_gather_kernel<<<NBUCK, 512, 0, stream>>>(Zs, ebufP, gcur, ovfc, ovfbuf, dinv, cvec, out, N);
}